// Round 12
// baseline (84.089 us; speedup 1.0000x reference)
//
#include <hip/hip_runtime.h>

// SupNet pair-distance head, v10: register-budget cut (<=128/wave) for
// 4 waves/SIMD residency. 16-j tile (rpf 32 regs), 4 acc chains, 3072 blocks.
//   rp16[j][c] = f16( z[j]·W1[c,:128] + b1[c] )
//   cp16[i][c] = f16( z[i]·W1[c,128:] )
//   h[m][c]  = relu(rp16 + cp16)            (f16 math)
//   h2[n][m] = relu( W2[n][:]·h[m][:] + b2[n] )
//   out[m][o]= Wf[o][:]·h2[:][m] + bf[o]
//
// MFMA 16x16x32 f16. 4 waves/block (wave nh owns 32 n-channels),
// job = 2 i x 16 j, 6 jobs/block. Barrier-free main loop.

typedef __attribute__((ext_vector_type(8)))  _Float16 f16x8;
typedef __attribute__((ext_vector_type(2)))  float    f32x2;
typedef __attribute__((ext_vector_type(4)))  float    f32x4;

#define NCELL 768
#define DIM   128
#define C1    256
#define C2    128

// LDS map (bytes)
#define CPL    0          // 12 rows * 512B cp16
#define TABA   6144       // 64 n-pairs * 16B {b2[n0],b2[n1],wf0[n0],wf0[n1]}
#define TABB   7168       // 64 n-pairs * 8B  {wf1[n0],wf1[n1]}
#define CBo    7680       // 4 nh * 192 pairs * 8B partials (nh-major)
#define LDS_SZ 13824

#define MFMA16(a, b, c) __builtin_amdgcn_mfma_f32_16x16x32_f16(a, b, c, 0, 0, 0)

// ---------------------------------------------------------------- helpers
static __device__ __forceinline__ f32x2 pk_add(f32x2 a, f32x2 b) {
    f32x2 d; asm("v_pk_add_f32 %0, %1, %2" : "=v"(d) : "v"(a), "v"(b)); return d;
}
static __device__ __forceinline__ f32x2 pk_fma(f32x2 a, f32x2 b, f32x2 c) {
    f32x2 d; asm("v_pk_fma_f32 %0, %1, %2, %3" : "=v"(d) : "v"(a), "v"(b), "v"(c)); return d;
}
static __device__ __forceinline__ f32x2 relu2(f32x2 a) {
    f32x2 d; d[0] = fmaxf(a[0], 0.f); d[1] = fmaxf(a[1], 0.f); return d;
}
static __device__ __forceinline__ f32x2 lo2(f32x4 v) { return __builtin_shufflevector(v, v, 0, 1); }
static __device__ __forceinline__ f32x2 hi2(f32x4 v) { return __builtin_shufflevector(v, v, 2, 3); }

// ---------------------------------------------------------------- fused prep
// blocks 0..191: rp16/cp16 for 4 j's each; blocks 192..319: W2 -> f16.
__global__ __launch_bounds__(256) void prep_all(const float* __restrict__ z,
                                                const float* __restrict__ W1,
                                                const float* __restrict__ b1,
                                                const float* __restrict__ W2,
                                                _Float16* __restrict__ rp16,
                                                _Float16* __restrict__ cp16,
                                                _Float16* __restrict__ w2h) {
    const int tid = threadIdx.x;
    if (blockIdx.x < 192) {
        const int jb4 = blockIdx.x * 4;
        __shared__ float zl[4 * DIM];
        zl[tid]       = z[(size_t)jb4 * DIM + tid];
        zl[tid + 256] = z[(size_t)jb4 * DIM + tid + 256];
        __syncthreads();
        const int o = tid;
        float a1[4] = {0.f, 0.f, 0.f, 0.f};
        float a2[4] = {0.f, 0.f, 0.f, 0.f};
        const f32x4* w4 = (const f32x4*)(W1 + (size_t)o * (2 * DIM));
#pragma unroll 4
        for (int d4 = 0; d4 < 32; ++d4) {
            f32x4 wa = w4[d4], wb = w4[32 + d4];
#pragma unroll
            for (int jj = 0; jj < 4; ++jj) {
                f32x4 zv = *(const f32x4*)(zl + jj * DIM + d4 * 4);
#pragma unroll
                for (int e = 0; e < 4; ++e) {
                    a1[jj] = fmaf(zv[e], wa[e], a1[jj]);
                    a2[jj] = fmaf(zv[e], wb[e], a2[jj]);
                }
            }
        }
        const float bb = b1[o];
#pragma unroll
        for (int jj = 0; jj < 4; ++jj) {
            rp16[(size_t)(jb4 + jj) * C1 + o] = (_Float16)(a1[jj] + bb);
            cp16[(size_t)(jb4 + jj) * C1 + o] = (_Float16)a2[jj];
        }
    } else {
        const int t = (blockIdx.x - 192) * 256 + tid;   // 0..32767
        w2h[t] = (_Float16)W2[t];
    }
}

// ---------------------------------------------------------------- main kernel
// grid = 48 jbg * 64 ic = 3072 blocks * 256 thr; 6 jobs * 2 i, 16 j.
__global__ __launch_bounds__(256, 4) void pair_head(const _Float16* __restrict__ rp16,
                                                    const _Float16* __restrict__ cp16,
                                                    const _Float16* __restrict__ w2h,
                                                    const float* __restrict__ Wf,
                                                    const float* __restrict__ b2,
                                                    const float* __restrict__ bfv,
                                                    float* __restrict__ out) {
    __shared__ char smem[LDS_SZ];
    const int tid = threadIdx.x;
    const int nh  = tid >> 6;      // wave id = n-quarter
    const int l   = tid & 63;
    const int lc  = l & 15;        // fragment col/row index
    const int lg  = l >> 4;        // k-group 0..3
    const int jbg = blockIdx.x >> 6;     // 0..47
    const int ic  = blockIdx.x & 63;     // 0..63
    const int j0  = jbg * 16;
    const int i_base = ic * 12;

    // ---- stage all 12 cp rows (6 KB) once
#pragma unroll
    for (int q = 0; q < 6; ++q) {
        int off = q * 256 + tid;   // u32 index, 1536 total
        ((unsigned*)(smem + CPL))[off] =
            ((const unsigned*)(cp16 + (size_t)i_base * C1))[off];
    }
    // ---- n-pair tables: n0 = 2*np
    if (tid < 64) {
        int n0 = 2 * tid;
        f32x4 A = {b2[n0], b2[n0 + 1], Wf[n0], Wf[n0 + 1]};
        f32x2 B = {Wf[C2 + n0], Wf[C2 + n0 + 1]};
        *(f32x4*)(smem + TABA + tid * 16) = A;
        *(f32x2*)(smem + TABB + tid * 8)  = B;
    }

    // ---- rp B-fragments in registers (32 VGPRs), constant over all jobs
    f16x8 rpf[8];
#pragma unroll
    for (int ks = 0; ks < 8; ++ks)
        rpf[ks] = *(const f16x8*)(rp16 + (size_t)(j0 + lc) * C1 + lg * 8 + ks * 32);

    // ---- W2 A-fragments for this wave's 32 n-channels (64 VGPRs)
    f16x8 w2f[2][8];
#pragma unroll
    for (int ng = 0; ng < 2; ++ng)
#pragma unroll
        for (int ks = 0; ks < 8; ++ks)
            w2f[ng][ks] = *(const f16x8*)(w2h + (size_t)(nh * 32 + ng * 16 + lc) * C1 + lg * 8 + ks * 32);

    __syncthreads();

    const f16x8 z8 = (f16x8)(_Float16)0.0f;

#pragma unroll 1
    for (int t = 0; t < 6; ++t) {
        const char* c0 = smem + CPL + (2 * t) * 512 + lg * 16;

        f32x4 ac[2][2];   // [ng][ii]
#pragma unroll
        for (int g = 0; g < 2; ++g)
#pragma unroll
            for (int c = 0; c < 2; ++c) ac[g][c] = (f32x4)0.f;

#pragma unroll
        for (int ks = 0; ks < 8; ++ks) {
            f16x8 cv0 = *(const f16x8*)(c0 + ks * 64);          // i = 2t
            f16x8 cv1 = *(const f16x8*)(c0 + 512 + ks * 64);    // i = 2t+1
            f16x8 hb0 = __builtin_elementwise_max(rpf[ks] + cv0, z8);
            ac[0][0] = MFMA16(w2f[0][ks], hb0, ac[0][0]);
            ac[1][0] = MFMA16(w2f[1][ks], hb0, ac[1][0]);
            f16x8 hb1 = __builtin_elementwise_max(rpf[ks] + cv1, z8);
            ac[0][1] = MFMA16(w2f[0][ks], hb1, ac[0][1]);
            ac[1][1] = MFMA16(w2f[1][ks], hb1, ac[1][1]);
        }

        // ---- epilogue (packed): h2 = relu(acc + b2); partial Wf-dot
        f32x2 P0[2], P1[2];
#pragma unroll
        for (int c = 0; c < 2; ++c) { P0[c] = (f32x2){0.f, 0.f}; P1[c] = (f32x2){0.f, 0.f}; }
#pragma unroll
        for (int ng = 0; ng < 2; ++ng) {
#pragma unroll
            for (int rp2 = 0; rp2 < 2; ++rp2) {
                int np = nh * 16 + ng * 8 + lg * 2 + rp2;
                f32x4 A = *(const f32x4*)(smem + TABA + np * 16);
                f32x2 B = *(const f32x2*)(smem + TABB + np * 8);
#pragma unroll
                for (int c = 0; c < 2; ++c) {
                    f32x2 s = {ac[ng][c][2 * rp2], ac[ng][c][2 * rp2 + 1]};
                    s = relu2(pk_add(s, lo2(A)));
                    P0[c] = pk_fma(hi2(A), s, P0[c]);
                    P1[c] = pk_fma(B, s, P1[c]);
                }
            }
        }
        // reduce over lane-groups (pair col = l&15), then publish partials
#pragma unroll
        for (int c = 0; c < 2; ++c) {
            float p0 = P0[c][0] + P0[c][1];
            float p1 = P1[c][0] + P1[c][1];
            p0 += __shfl_xor(p0, 16); p1 += __shfl_xor(p1, 16);
            p0 += __shfl_xor(p0, 32); p1 += __shfl_xor(p1, 32);
            if (l < 16) {
                int p = t * 32 + c * 16 + l;   // pair index within block
                *(f32x2*)(smem + CBo + nh * 1536 + p * 8) = (f32x2){p0, p1};
            }
        }
    }

    __syncthreads();

    // ---- final combine: 192 pairs, sum the 4 n-quarter partials
    const float bf0 = bfv[0], bf1 = bfv[1];
    if (tid < 192) {
        const int p = tid;
        f32x2 a0 = *(const f32x2*)(smem + CBo +        p * 8);
        f32x2 a1 = *(const f32x2*)(smem + CBo + 1536 + p * 8);
        f32x2 a2 = *(const f32x2*)(smem + CBo + 3072 + p * 8);
        f32x2 a3 = *(const f32x2*)(smem + CBo + 4608 + p * 8);
        float o0 = a0[0] + a1[0] + a2[0] + a3[0] + bf0;
        float o1 = a0[1] + a1[1] + a2[1] + a3[1] + bf1;
        int c = p & 15, ii = (p >> 4) & 1, t = p >> 5;
        int i = i_base + 2 * t + ii;
        int j = j0 + c;
        *(f32x2*)(out + ((size_t)i * NCELL + j) * 2) = (f32x2){o0, o1};
    }
}

// ---------------------------------------------------------------- launcher
extern "C" void kernel_launch(void* const* d_in, const int* in_sizes, int n_in,
                              void* d_out, int out_size, void* d_ws, size_t ws_size,
                              hipStream_t stream) {
    const float* z   = (const float*)d_in[0];
    const float* W1  = (const float*)d_in[1];
    const float* b1  = (const float*)d_in[2];
    const float* W2  = (const float*)d_in[3];
    const float* b2  = (const float*)d_in[4];
    const float* Wf  = (const float*)d_in[5];
    const float* bfv = (const float*)d_in[6];
    float* out = (float*)d_out;

    _Float16* rp16 = (_Float16*)d_ws;                 // 768*256 f16
    _Float16* cp16 = rp16 + NCELL * C1;               // 768*256 f16
    _Float16* w2h  = cp16 + NCELL * C1;               // 128*256 f16

    prep_all<<<192 + 128, 256, 0, stream>>>(z, W1, b1, W2, rp16, cp16, w2h);
    pair_head<<<48 * 64, 256, 0, stream>>>(rp16, cp16, w2h, Wf, b2, bfv, out);
}

// Round 13
// 66.162 us; speedup vs baseline: 1.2710x; 1.2710x over previous
//
#include <hip/hip_runtime.h>

// SupNet pair-distance head, v11: v10 tiling with __launch_bounds__(256,3) —
// 3 waves/SIMD budget (<=170 regs) so fragment state fits WITHOUT spill.
//   rp16[j][c] = f16( z[j]·W1[c,:128] + b1[c] )
//   cp16[i][c] = f16( z[i]·W1[c,128:] )
//   h[m][c]  = relu(rp16 + cp16)            (f16 math)
//   h2[n][m] = relu( W2[n][:]·h[m][:] + b2[n] )
//   out[m][o]= Wf[o][:]·h2[:][m] + bf[o]
//
// MFMA 16x16x32 f16. 4 waves/block (wave nh owns 32 n-channels),
// job = 2 i x 16 j, 6 jobs/block. Barrier-free main loop.

typedef __attribute__((ext_vector_type(8)))  _Float16 f16x8;
typedef __attribute__((ext_vector_type(2)))  float    f32x2;
typedef __attribute__((ext_vector_type(4)))  float    f32x4;

#define NCELL 768
#define DIM   128
#define C1    256
#define C2    128

// LDS map (bytes)
#define CPL    0          // 12 rows * 512B cp16
#define TABA   6144       // 64 n-pairs * 16B {b2[n0],b2[n1],wf0[n0],wf0[n1]}
#define TABB   7168       // 64 n-pairs * 8B  {wf1[n0],wf1[n1]}
#define CBo    7680       // 4 nh * 192 pairs * 8B partials (nh-major)
#define LDS_SZ 13824

#define MFMA16(a, b, c) __builtin_amdgcn_mfma_f32_16x16x32_f16(a, b, c, 0, 0, 0)

// ---------------------------------------------------------------- helpers
static __device__ __forceinline__ f32x2 pk_add(f32x2 a, f32x2 b) {
    f32x2 d; asm("v_pk_add_f32 %0, %1, %2" : "=v"(d) : "v"(a), "v"(b)); return d;
}
static __device__ __forceinline__ f32x2 pk_fma(f32x2 a, f32x2 b, f32x2 c) {
    f32x2 d; asm("v_pk_fma_f32 %0, %1, %2, %3" : "=v"(d) : "v"(a), "v"(b), "v"(c)); return d;
}
static __device__ __forceinline__ f32x2 relu2(f32x2 a) {
    f32x2 d; d[0] = fmaxf(a[0], 0.f); d[1] = fmaxf(a[1], 0.f); return d;
}
static __device__ __forceinline__ f32x2 lo2(f32x4 v) { return __builtin_shufflevector(v, v, 0, 1); }
static __device__ __forceinline__ f32x2 hi2(f32x4 v) { return __builtin_shufflevector(v, v, 2, 3); }

// ---------------------------------------------------------------- fused prep
// blocks 0..191: rp16/cp16 for 4 j's each; blocks 192..319: W2 -> f16.
__global__ __launch_bounds__(256) void prep_all(const float* __restrict__ z,
                                                const float* __restrict__ W1,
                                                const float* __restrict__ b1,
                                                const float* __restrict__ W2,
                                                _Float16* __restrict__ rp16,
                                                _Float16* __restrict__ cp16,
                                                _Float16* __restrict__ w2h) {
    const int tid = threadIdx.x;
    if (blockIdx.x < 192) {
        const int jb4 = blockIdx.x * 4;
        __shared__ float zl[4 * DIM];
        zl[tid]       = z[(size_t)jb4 * DIM + tid];
        zl[tid + 256] = z[(size_t)jb4 * DIM + tid + 256];
        __syncthreads();
        const int o = tid;
        float a1[4] = {0.f, 0.f, 0.f, 0.f};
        float a2[4] = {0.f, 0.f, 0.f, 0.f};
        const f32x4* w4 = (const f32x4*)(W1 + (size_t)o * (2 * DIM));
#pragma unroll 4
        for (int d4 = 0; d4 < 32; ++d4) {
            f32x4 wa = w4[d4], wb = w4[32 + d4];
#pragma unroll
            for (int jj = 0; jj < 4; ++jj) {
                f32x4 zv = *(const f32x4*)(zl + jj * DIM + d4 * 4);
#pragma unroll
                for (int e = 0; e < 4; ++e) {
                    a1[jj] = fmaf(zv[e], wa[e], a1[jj]);
                    a2[jj] = fmaf(zv[e], wb[e], a2[jj]);
                }
            }
        }
        const float bb = b1[o];
#pragma unroll
        for (int jj = 0; jj < 4; ++jj) {
            rp16[(size_t)(jb4 + jj) * C1 + o] = (_Float16)(a1[jj] + bb);
            cp16[(size_t)(jb4 + jj) * C1 + o] = (_Float16)a2[jj];
        }
    } else {
        const int t = (blockIdx.x - 192) * 256 + tid;   // 0..32767
        w2h[t] = (_Float16)W2[t];
    }
}

// ---------------------------------------------------------------- main kernel
// grid = 48 jbg * 64 ic = 3072 blocks * 256 thr; 6 jobs * 2 i, 16 j.
__global__ __launch_bounds__(256, 3) void pair_head(const _Float16* __restrict__ rp16,
                                                    const _Float16* __restrict__ cp16,
                                                    const _Float16* __restrict__ w2h,
                                                    const float* __restrict__ Wf,
                                                    const float* __restrict__ b2,
                                                    const float* __restrict__ bfv,
                                                    float* __restrict__ out) {
    __shared__ char smem[LDS_SZ];
    const int tid = threadIdx.x;
    const int nh  = tid >> 6;      // wave id = n-quarter
    const int l   = tid & 63;
    const int lc  = l & 15;        // fragment col/row index
    const int lg  = l >> 4;        // k-group 0..3
    const int jbg = blockIdx.x >> 6;     // 0..47
    const int ic  = blockIdx.x & 63;     // 0..63
    const int j0  = jbg * 16;
    const int i_base = ic * 12;

    // ---- stage all 12 cp rows (6 KB) once
#pragma unroll
    for (int q = 0; q < 6; ++q) {
        int off = q * 256 + tid;   // u32 index, 1536 total
        ((unsigned*)(smem + CPL))[off] =
            ((const unsigned*)(cp16 + (size_t)i_base * C1))[off];
    }
    // ---- n-pair tables: n0 = 2*np
    if (tid < 64) {
        int n0 = 2 * tid;
        f32x4 A = {b2[n0], b2[n0 + 1], Wf[n0], Wf[n0 + 1]};
        f32x2 B = {Wf[C2 + n0], Wf[C2 + n0 + 1]};
        *(f32x4*)(smem + TABA + tid * 16) = A;
        *(f32x2*)(smem + TABB + tid * 8)  = B;
    }

    // ---- rp B-fragments in registers (32 VGPRs), constant over all jobs
    f16x8 rpf[8];
#pragma unroll
    for (int ks = 0; ks < 8; ++ks)
        rpf[ks] = *(const f16x8*)(rp16 + (size_t)(j0 + lc) * C1 + lg * 8 + ks * 32);

    // ---- W2 A-fragments for this wave's 32 n-channels (64 VGPRs)
    f16x8 w2f[2][8];
#pragma unroll
    for (int ng = 0; ng < 2; ++ng)
#pragma unroll
        for (int ks = 0; ks < 8; ++ks)
            w2f[ng][ks] = *(const f16x8*)(w2h + (size_t)(nh * 32 + ng * 16 + lc) * C1 + lg * 8 + ks * 32);

    __syncthreads();

    const f16x8 z8 = (f16x8)(_Float16)0.0f;

#pragma unroll 1
    for (int t = 0; t < 6; ++t) {
        const char* c0 = smem + CPL + (2 * t) * 512 + lg * 16;

        f32x4 ac[2][2];   // [ng][ii]
#pragma unroll
        for (int g = 0; g < 2; ++g)
#pragma unroll
            for (int c = 0; c < 2; ++c) ac[g][c] = (f32x4)0.f;

#pragma unroll
        for (int ks = 0; ks < 8; ++ks) {
            f16x8 cv0 = *(const f16x8*)(c0 + ks * 64);          // i = 2t
            f16x8 cv1 = *(const f16x8*)(c0 + 512 + ks * 64);    // i = 2t+1
            f16x8 hb0 = __builtin_elementwise_max(rpf[ks] + cv0, z8);
            ac[0][0] = MFMA16(w2f[0][ks], hb0, ac[0][0]);
            ac[1][0] = MFMA16(w2f[1][ks], hb0, ac[1][0]);
            f16x8 hb1 = __builtin_elementwise_max(rpf[ks] + cv1, z8);
            ac[0][1] = MFMA16(w2f[0][ks], hb1, ac[0][1]);
            ac[1][1] = MFMA16(w2f[1][ks], hb1, ac[1][1]);
        }

        // ---- epilogue (packed): h2 = relu(acc + b2); partial Wf-dot
        f32x2 P0[2], P1[2];
#pragma unroll
        for (int c = 0; c < 2; ++c) { P0[c] = (f32x2){0.f, 0.f}; P1[c] = (f32x2){0.f, 0.f}; }
#pragma unroll
        for (int ng = 0; ng < 2; ++ng) {
#pragma unroll
            for (int rp2 = 0; rp2 < 2; ++rp2) {
                int np = nh * 16 + ng * 8 + lg * 2 + rp2;
                f32x4 A = *(const f32x4*)(smem + TABA + np * 16);
                f32x2 B = *(const f32x2*)(smem + TABB + np * 8);
#pragma unroll
                for (int c = 0; c < 2; ++c) {
                    f32x2 s = {ac[ng][c][2 * rp2], ac[ng][c][2 * rp2 + 1]};
                    s = relu2(pk_add(s, lo2(A)));
                    P0[c] = pk_fma(hi2(A), s, P0[c]);
                    P1[c] = pk_fma(B, s, P1[c]);
                }
            }
        }
        // reduce over lane-groups (pair col = l&15), then publish partials
#pragma unroll
        for (int c = 0; c < 2; ++c) {
            float p0 = P0[c][0] + P0[c][1];
            float p1 = P1[c][0] + P1[c][1];
            p0 += __shfl_xor(p0, 16); p1 += __shfl_xor(p1, 16);
            p0 += __shfl_xor(p0, 32); p1 += __shfl_xor(p1, 32);
            if (l < 16) {
                int p = t * 32 + c * 16 + l;   // pair index within block
                *(f32x2*)(smem + CBo + nh * 1536 + p * 8) = (f32x2){p0, p1};
            }
        }
    }

    __syncthreads();

    // ---- final combine: 192 pairs, sum the 4 n-quarter partials
    const float bf0 = bfv[0], bf1 = bfv[1];
    if (tid < 192) {
        const int p = tid;
        f32x2 a0 = *(const f32x2*)(smem + CBo +        p * 8);
        f32x2 a1 = *(const f32x2*)(smem + CBo + 1536 + p * 8);
        f32x2 a2 = *(const f32x2*)(smem + CBo + 3072 + p * 8);
        f32x2 a3 = *(const f32x2*)(smem + CBo + 4608 + p * 8);
        float o0 = a0[0] + a1[0] + a2[0] + a3[0] + bf0;
        float o1 = a0[1] + a1[1] + a2[1] + a3[1] + bf1;
        int c = p & 15, ii = (p >> 4) & 1, t = p >> 5;
        int i = i_base + 2 * t + ii;
        int j = j0 + c;
        *(f32x2*)(out + ((size_t)i * NCELL + j) * 2) = (f32x2){o0, o1};
    }
}

// ---------------------------------------------------------------- launcher
extern "C" void kernel_launch(void* const* d_in, const int* in_sizes, int n_in,
                              void* d_out, int out_size, void* d_ws, size_t ws_size,
                              hipStream_t stream) {
    const float* z   = (const float*)d_in[0];
    const float* W1  = (const float*)d_in[1];
    const float* b1  = (const float*)d_in[2];
    const float* W2  = (const float*)d_in[3];
    const float* b2  = (const float*)d_in[4];
    const float* Wf  = (const float*)d_in[5];
    const float* bfv = (const float*)d_in[6];
    float* out = (float*)d_out;

    _Float16* rp16 = (_Float16*)d_ws;                 // 768*256 f16
    _Float16* cp16 = rp16 + NCELL * C1;               // 768*256 f16
    _Float16* w2h  = cp16 + NCELL * C1;               // 128*256 f16

    prep_all<<<192 + 128, 256, 0, stream>>>(z, W1, b1, W2, rp16, cp16, w2h);
    pair_head<<<48 * 64, 256, 0, stream>>>(rp16, cp16, w2h, Wf, b2, bfv, out);
}